// Round 1
// baseline (1092.645 us; speedup 1.0000x reference)
//
#include <hip/hip_runtime.h>

// Problem constants (from reference): N_INST=8192, SEQ_LEN=32, HIDDEN=768,
// PROJ_DIM=128, N_FUNC=512.
constexpr int SEQ   = 32;
constexpr int HID   = 768;
constexpr int F4    = HID / 4;   // 192 float4 per hidden row
constexpr int PROJ  = 128;
constexpr int NFUNC = 512;
constexpr int RB    = 8;         // rows per block in GEMM1

// ---------------------------------------------------------------------------
// Kernel 1: fused (mean over seq) + (mean over instance segment).
// One block per function; its segment of enc is a contiguous
// (end-start)*SEQ x HID region. 192 threads each own one float4 column.
// ---------------------------------------------------------------------------
__global__ __launch_bounds__(192) void k_reduce(const float* __restrict__ enc,
                                                const int* __restrict__ bounds,
                                                float* __restrict__ fe) {
  const int f = blockIdx.x;
  const int t = threadIdx.x;
  const int start = bounds[2 * f];
  const int end   = bounds[2 * f + 1];
  const long rows = (long)(end - start) * SEQ;
  const float4* __restrict__ p =
      reinterpret_cast<const float4*>(enc) + (size_t)start * SEQ * F4 + t;

  float4 a[8];
#pragma unroll
  for (int i = 0; i < 8; ++i) a[i] = make_float4(0.f, 0.f, 0.f, 0.f);

  long r = 0;
  for (; r + 8 <= rows; r += 8) {
#pragma unroll
    for (int i = 0; i < 8; ++i) {
      float4 v = p[(size_t)(r + i) * F4];
      a[i].x += v.x; a[i].y += v.y; a[i].z += v.z; a[i].w += v.w;
    }
  }
  for (; r < rows; ++r) {
    float4 v = p[(size_t)r * F4];
    a[0].x += v.x; a[0].y += v.y; a[0].z += v.z; a[0].w += v.w;
  }
#pragma unroll
  for (int i = 1; i < 8; ++i) {
    a[0].x += a[i].x; a[0].y += a[i].y; a[0].z += a[i].z; a[0].w += a[i].w;
  }
  const float inv = 1.0f / ((float)(end - start) * (float)SEQ);
  a[0].x *= inv; a[0].y *= inv; a[0].z *= inv; a[0].w *= inv;
  reinterpret_cast<float4*>(fe)[(size_t)f * F4 + t] = a[0];
}

// ---------------------------------------------------------------------------
// Kernel 2: h = relu(func_embs @ W1 + b1).  (512x768)@(768x768).
// Block: 256 threads = 256 consecutive columns; RB=8 rows staged in LDS.
// W1[k][c] reads are coalesced across threads; fs[r][k] is an LDS broadcast.
// ---------------------------------------------------------------------------
__global__ __launch_bounds__(256) void k_gemm1(const float* __restrict__ fe,
                                               const float* __restrict__ W1,
                                               const float* __restrict__ b1,
                                               float* __restrict__ h) {
  __shared__ float fs[RB][HID];
  const int tx = threadIdx.x;
  const int c  = blockIdx.x * 256 + tx;
  const int r0 = blockIdx.y * RB;

  for (int i = tx; i < RB * HID; i += 256) {
    fs[i / HID][i % HID] = fe[(size_t)(r0 + i / HID) * HID + (i % HID)];
  }
  __syncthreads();

  float acc[RB];
#pragma unroll
  for (int r = 0; r < RB; ++r) acc[r] = 0.f;

  for (int k = 0; k < HID; k += 4) {
    const float w0 = W1[(size_t)(k + 0) * HID + c];
    const float w1 = W1[(size_t)(k + 1) * HID + c];
    const float w2 = W1[(size_t)(k + 2) * HID + c];
    const float w3 = W1[(size_t)(k + 3) * HID + c];
#pragma unroll
    for (int r = 0; r < RB; ++r) {
      acc[r] = fmaf(fs[r][k + 0], w0, acc[r]);
      acc[r] = fmaf(fs[r][k + 1], w1, acc[r]);
      acc[r] = fmaf(fs[r][k + 2], w2, acc[r]);
      acc[r] = fmaf(fs[r][k + 3], w3, acc[r]);
    }
  }
  const float bias = b1[c];
#pragma unroll
  for (int r = 0; r < RB; ++r)
    h[(size_t)(r0 + r) * HID + c] = fmaxf(acc[r] + bias, 0.f);
}

// ---------------------------------------------------------------------------
// Kernel 3: out = normalize_rows(h @ W2 + b2).  (512x768)@(768x128).
// One block per output row, 128 threads = 128 output columns.
// ---------------------------------------------------------------------------
__global__ __launch_bounds__(128) void k_gemm2(const float* __restrict__ h,
                                               const float* __restrict__ W2,
                                               const float* __restrict__ b2,
                                               float* __restrict__ out) {
  __shared__ float hs[HID];
  __shared__ float red[2];
  const int r  = blockIdx.x;
  const int tx = threadIdx.x;

  for (int i = tx; i < HID; i += 128) hs[i] = h[(size_t)r * HID + i];
  __syncthreads();

  float acc = 0.f;
  for (int k = 0; k < HID; k += 8) {
#pragma unroll
    for (int kk = 0; kk < 8; ++kk)
      acc = fmaf(hs[k + kk], W2[(size_t)(k + kk) * PROJ + tx], acc);
  }
  const float v = acc + b2[tx];

  float ss = v * v;
#pragma unroll
  for (int off = 32; off > 0; off >>= 1) ss += __shfl_xor(ss, off, 64);
  if ((tx & 63) == 0) red[tx >> 6] = ss;
  __syncthreads();
  const float total = red[0] + red[1];
  const float scale = 1.0f / fmaxf(sqrtf(total), 1e-12f);
  out[(size_t)r * PROJ + tx] = v * scale;
}

// ---------------------------------------------------------------------------
extern "C" void kernel_launch(void* const* d_in, const int* in_sizes, int n_in,
                              void* d_out, int out_size, void* d_ws, size_t ws_size,
                              hipStream_t stream) {
  const float* enc    = (const float*)d_in[0];
  const float* W1     = (const float*)d_in[1];
  const float* b1     = (const float*)d_in[2];
  const float* W2     = (const float*)d_in[3];
  const float* b2     = (const float*)d_in[4];
  const int*   bounds = (const int*)d_in[5];
  float* out = (float*)d_out;

  float* fe = (float*)d_ws;                  // 512*768 fp32 = 1.5 MB
  float* h  = fe + (size_t)NFUNC * HID;      // 512*768 fp32 = 1.5 MB

  k_reduce<<<NFUNC, 192, 0, stream>>>(enc, bounds, fe);

  dim3 g1(HID / 256, NFUNC / RB);
  k_gemm1<<<g1, 256, 0, stream>>>(fe, W1, b1, h);

  k_gemm2<<<NFUNC, 128, 0, stream>>>(h, W2, b2, out);
}